// Round 15
// baseline (872.693 us; speedup 1.0000x reference)
//
#include <hip/hip_runtime.h>
#include <hip/hip_bf16.h>
#include <cstdint>

#define NTOK 4096
#define HID  2048
#define ITER 768
#define NEXP 64
#define TOPK 8
#define MAXT 320   // max 256-row tiles: 32768/256 + 63 padding tiles

typedef __attribute__((ext_vector_type(8))) short sh8;
typedef __attribute__((ext_vector_type(4))) float f32x4;

#define MFMA16 __builtin_amdgcn_mfma_f32_16x16x32_bf16

__device__ __forceinline__ uint16_t f2b(float f) {
  union { float f; uint32_t u; } v; v.f = f;
  uint32_t u = v.u;
  u += 0x7FFFu + ((u >> 16) & 1u);   // RNE
  return (uint16_t)(u >> 16);
}

__device__ __forceinline__ float b2f_lo(uint32_t w) {   // bf16 in bits[15:0]
  union { uint32_t u; float f; } v; v.u = w << 16; return v.f;
}
__device__ __forceinline__ float b2f_hi(uint32_t w) {   // bf16 in bits[31:16]
  union { uint32_t u; float f; } v; v.u = w & 0xffff0000u; return v.f;
}

__device__ __forceinline__ uint32_t cvtpk(float lo, float hi) {
  float2 f2; f2.x = lo; f2.y = hi;
  __hip_bfloat162 h = __float22bfloat162_rn(f2);
  union { __hip_bfloat162 h; uint32_t u; } v; v.h = h;
  return v.u;
}

__device__ __forceinline__ void gl2lds16(const void* g, void* l) {
  __builtin_amdgcn_global_load_lds(
      (const __attribute__((address_space(1))) uint32_t*)g,
      (__attribute__((address_space(3))) uint32_t*)l, 16, 0, 0);
}

// m204 bijective XCD-chunked swizzle: hw slot s -> logical L (contiguous L per XCD)
__device__ __forceinline__ int xcd_unswizzle(int s, int na) {
  int q = na >> 3, r = na & 7, x = s & 7, i = s >> 3;
  return (x < r ? x * (q + 1) : r * (q + 1) + (x - r) * q) + i;
}

// ---------------- zero histogram state ----------------
__global__ void zero_kernel(int* __restrict__ cc) {
  cc[threadIdx.x] = 0;   // counts[64] + cursor[64]
}

// ---------------- x fp32 -> bf16 ----------------
__global__ __launch_bounds__(256) void xcast_kernel(const float* __restrict__ x,
                                                    uint16_t* __restrict__ xb) {
  size_t i = ((size_t)blockIdx.x * 256 + threadIdx.x) * 8;
  float4 a = *(const float4*)(x + i);
  float4 b = *(const float4*)(x + i + 4);
  uint4 o;
  o.x = (uint32_t)f2b(a.x) | ((uint32_t)f2b(a.y) << 16);
  o.y = (uint32_t)f2b(a.z) | ((uint32_t)f2b(a.w) << 16);
  o.z = (uint32_t)f2b(b.x) | ((uint32_t)f2b(b.y) << 16);
  o.w = (uint32_t)f2b(b.z) | ((uint32_t)f2b(b.w) << 16);
  *(uint4*)(xb + i) = o;
}

// ---------------- router: logits + top8 + softmax + histogram ----------------
__global__ __launch_bounds__(256) void router_kernel(
    const float* __restrict__ x, const float* __restrict__ gate_w,
    float* __restrict__ logits, int* __restrict__ topk_id,
    float* __restrict__ topk_w, int* __restrict__ counts)
{
  int lane = threadIdx.x & 63;
  int wv   = threadIdx.x >> 6;
  int t    = blockIdx.x * 4 + wv;
  const float* xr = x + (size_t)t * HID;
  float acc = 0.f;
  #pragma unroll 4
  for (int h = 0; h < HID; h += 4) {
    float4 xv = *(const float4*)(xr + h);
    acc += xv.x * gate_w[(h + 0) * NEXP + lane];
    acc += xv.y * gate_w[(h + 1) * NEXP + lane];
    acc += xv.z * gate_w[(h + 2) * NEXP + lane];
    acc += xv.w * gate_w[(h + 3) * NEXP + lane];
  }
  logits[(size_t)t * NEXP + lane] = acc;

  float v = acc;
  float topv[TOPK]; int topi[TOPK];
  #pragma unroll
  for (int k = 0; k < TOPK; ++k) {
    float bv = v; int bi = lane;
    #pragma unroll
    for (int off = 32; off > 0; off >>= 1) {
      float ov = __shfl_xor(bv, off);
      int   oi = __shfl_xor(bi, off);
      if (ov > bv || (ov == bv && oi < bi)) { bv = ov; bi = oi; }
    }
    topv[k] = bv; topi[k] = bi;
    if (lane == bi) v = -3.0e38f;
  }
  float m = topv[0], s = 0.f, w[TOPK];
  #pragma unroll
  for (int k = 0; k < TOPK; ++k) { w[k] = __expf(topv[k] - m); s += w[k]; }
  float inv = 1.f / s;
  if (lane < TOPK) {
    topk_id[t * TOPK + lane] = topi[lane];
    topk_w[t * TOPK + lane]  = w[lane] * inv;
    atomicAdd(&counts[topi[lane]], 1);
  }
}

// ---------------- offsets + dense tile list (256-row granularity) ----------------
__global__ void offsets_kernel(const int* __restrict__ counts, int* __restrict__ offsets,
                               int* __restrict__ tiles, int* __restrict__ tilecount) {
  if (threadIdx.x == 0) {
    int s = 0, nt = 0;
    for (int e = 0; e < NEXP; ++e) {
      offsets[e] = s;
      int c = counts[e];
      for (int rb = 0; rb * 256 < c; ++rb) tiles[nt++] = (e << 16) | rb;
      s += c;
    }
    offsets[NEXP] = s;
    tilecount[0] = nt;
  }
}

// ---------------- scatter pairs grouped by expert (+ inverse map) ----------------
__global__ __launch_bounds__(256) void scatter_kernel(
    const int* __restrict__ topk_id,
    const int* __restrict__ offsets, int* __restrict__ cursor,
    int* __restrict__ pair_tok, int* __restrict__ inv)
{
  int p = blockIdx.x * 256 + threadIdx.x;   // pair index = t*8+k
  int e = topk_id[p];
  int pos = offsets[e] + atomicAdd(&cursor[e], 1);
  pair_tok[pos] = p;
  inv[p] = pos;
}

// ================= gate+up grouped GEMM, BM256 x BN256, T3 2-phase pipeline =================
// 1024 threads (16 waves, 4M x 4N). A+B double-buffered (128 KB LDS). One raw s_barrier
// per K-step with counted vmcnt(16): the 16 B-loads for tile k+2 stay in flight ACROSS
// the barrier; the 2 gl2lds for tile k+1 drain under the MFMA cluster.
__global__ __launch_bounds__(1024, 4) void gateup_kernel(
    const uint16_t* __restrict__ xb,
    const float* __restrict__ gate_proj,
    const float* __restrict__ up_proj,
    const int* __restrict__ pair_tok,
    const int* __restrict__ offsets,
    const int* __restrict__ tiles,
    const int* __restrict__ tilecount,
    uint16_t* __restrict__ act)
{
  const int nt = tilecount[0];
  const int na = nt * 6;
  if (blockIdx.x >= na) return;
  const int L  = xcd_unswizzle(blockIdx.x, na);
  const int ti = L % nt, nc = L / nt;
  const int te = tiles[ti];
  const int e = te >> 16, row0 = (te & 0xffff) * 256;
  const int start = offsets[e];
  const int count = offsets[e + 1] - start;
  const int nvalid = min(256, count - row0);

  __shared__ __align__(16) uint16_t aT[2 * 256 * 64];   // 2 x 32 KB
  __shared__ __align__(16) uint16_t bT[2 * 256 * 64];   // 2 x 32 KB
  __shared__ int s_tok[256];

  const int t = threadIdx.x, l = t & 63, w = t >> 6;
  if (t < 256)
    s_tok[t] = (t < nvalid) ? (pair_tok[start + row0 + t] >> 3) : 0;
  __syncthreads();

  // A staging (gl2lds; pre-swizzled per-lane source). 16 waves x 2 q = 32 row-groups of 8.
  const int sub = l >> 3;
  const int xk  = ((l & 7) ^ sub) << 3;
  const uint16_t* srcA[2]; char* dstA[2];
  #pragma unroll
  for (int q = 0; q < 2; ++q) {
    int rl = (w * 2 + q) * 8 + sub;
    srcA[q] = xb + (size_t)s_tok[rl] * HID + xk;
    dstA[q] = (char*)aT + (w * 2 + q) * 1024;
  }

  // B reg-staging: 1024 threads cover 256 rows x 4 k-quarters (16 k each)
  const int brow = t & 255;
  const int kk0  = (t >> 8) * 16;
  const int rcomb  = nc * 256 + brow;                    // combined interleaved col
  const int n_orig = ((rcomb >> 5) << 4) + (rcomb & 15); // orig col in [0,768)
  const int is_up  = (rcomb >> 4) & 1;
  const float* wsrc = (is_up ? up_proj : gate_proj)
                    + (size_t)e * HID * ITER + n_orig;   // [k][n] fp32, ldw=ITER
  uint16_t* bwr[2];
  #pragma unroll
  for (int s = 0; s < 2; ++s) {
    int kb = (kk0 * 2 + 16 * s) ^ ((brow & 7) << 4);
    bwr[s] = (uint16_t*)((char*)bT + brow * 128 + kb);
  }

  const int wr = w >> 2, wc = w & 3, lr = l & 15, hi = l >> 4;
  const int xorv = (lr & 7) << 4;

  f32x4 acc[4][4];
  #pragma unroll
  for (int mi = 0; mi < 4; ++mi)
    #pragma unroll
    for (int ni = 0; ni < 4; ++ni)
      acc[mi][ni] = (f32x4){0.f, 0.f, 0.f, 0.f};

  float va[16];
  // ---- prologue: tile 0 -> buf0 (B via regs, A via gl2lds); issue va <- tile 1 ----
  {
    float v0[16];
    const float* wp0 = wsrc + (size_t)kk0 * ITER;
    #pragma unroll
    for (int j = 0; j < 16; ++j) v0[j] = wp0[(size_t)j * ITER];
    {
      uint4 o0, o1;
      o0.x = cvtpk(v0[0],  v0[1]);  o0.y = cvtpk(v0[2],  v0[3]);
      o0.z = cvtpk(v0[4],  v0[5]);  o0.w = cvtpk(v0[6],  v0[7]);
      o1.x = cvtpk(v0[8],  v0[9]);  o1.y = cvtpk(v0[10], v0[11]);
      o1.z = cvtpk(v0[12], v0[13]); o1.w = cvtpk(v0[14], v0[15]);
      *(uint4*)bwr[0] = o0;
      *(uint4*)bwr[1] = o1;
    }
    #pragma unroll
    for (int q = 0; q < 2; ++q) gl2lds16(srcA[q], dstA[q]);
    const float* wp1 = wsrc + (size_t)(64 + kk0) * ITER;
    #pragma unroll
    for (int j = 0; j < 16; ++j) va[j] = wp1[(size_t)j * ITER];
  }
  __builtin_amdgcn_sched_barrier(0);
  asm volatile("s_waitcnt vmcnt(16) lgkmcnt(0)");   // drain gl2lds A(0); va(1) stays out
  __builtin_amdgcn_s_barrier();

  for (int kc = 0; kc < 32; ++kc) {
    const int cur = kc & 1, nxt = cur ^ 1;
    const int k1 = min(kc + 1, 31), k2 = min(kc + 2, 31);   // clamped: uniform vm counts
    // 1. consume va (tile k+1): cvt + swizzled ds_write into buf nxt
    {
      uint4 o0, o1;
      o0.x = cvtpk(va[0],  va[1]);  o0.y = cvtpk(va[2],  va[3]);
      o0.z = cvtpk(va[4],  va[5]);  o0.w = cvtpk(va[6],  va[7]);
      o1.x = cvtpk(va[8],  va[9]);  o1.y = cvtpk(va[10], va[11]);
      o1.z = cvtpk(va[12], va[13]); o1.w = cvtpk(va[14], va[15]);
      *(uint4*)(bwr[0] + nxt * 16384) = o0;
      *(uint4*)(bwr[1] + nxt * 16384) = o1;
    }
    // 2. issue gl2lds A(k+1) into buf nxt (drains under the MFMA below)
    #pragma unroll
    for (int q = 0; q < 2; ++q)
      gl2lds16(srcA[q] + k1 * 64, dstA[q] + nxt * 32768);
    // 3. issue va <- B(k+2) (stays in flight across the next barrier)
    {
      const float* wp = wsrc + (size_t)(k2 * 64 + kk0) * ITER;
      #pragma unroll
      for (int j = 0; j < 16; ++j) va[j] = wp[(size_t)j * ITER];
    }
    __builtin_amdgcn_sched_barrier(0);
    // 4. MFMA on buf cur
    __builtin_amdgcn_s_setprio(1);
    const char* aBuf = (const char*)aT + cur * 32768;
    const char* bBuf = (const char*)bT + cur * 32768;
    #pragma unroll
    for (int ks = 0; ks < 2; ++ks) {
      sh8 af[4], bf[4];
      #pragma unroll
      for (int mi = 0; mi < 4; ++mi)
        af[mi] = *(const sh8*)(aBuf +
                   (wr * 64 + mi * 16 + lr) * 128 + ((ks * 64 + hi * 16) ^ xorv));
      #pragma unroll
      for (int ni = 0; ni < 4; ++ni)
        bf[ni] = *(const sh8*)(bBuf +
                   (wc * 64 + ni * 16 + lr) * 128 + ((ks * 64 + hi * 16) ^ xorv));
      #pragma unroll
      for (int mi = 0; mi < 4; ++mi)
        #pragma unroll
        for (int ni = 0; ni < 4; ++ni)
          acc[mi][ni] = MFMA16(af[mi], bf[ni], acc[mi][ni], 0, 0, 0);
    }
    __builtin_amdgcn_s_setprio(0);
    __builtin_amdgcn_sched_barrier(0);
    // 5. counted drain: 2 gl2lds done, 16 va stay outstanding
    asm volatile("s_waitcnt vmcnt(16) lgkmcnt(0)");
    __builtin_amdgcn_s_barrier();
  }

  // epilogue: combined col blocks pair (even=gate, odd=up)
  #pragma unroll
  for (int mi = 0; mi < 4; ++mi)
    #pragma unroll
    for (int p = 0; p < 2; ++p)
      #pragma unroll
      for (int j = 0; j < 4; ++j) {
        int row = wr * 64 + mi * 16 + hi * 4 + j;
        if (row < nvalid) {
          float g = acc[mi][2 * p][j], u = acc[mi][2 * p + 1][j];
          float a = (g / (1.f + __expf(-g))) * u;
          int col = nc * 128 + (wc * 2 + p) * 16 + lr;
          act[(size_t)(start + row0 + row) * ITER + col] = f2b(a);
        }
      }
}

// ================= down grouped GEMM, BM256 x BN256, T3 2-phase pipeline =================
// 1024 threads; dense bf16 rows out (no atomics)
__global__ __launch_bounds__(1024, 4) void down_kernel(
    const uint16_t* __restrict__ act,
    const float* __restrict__ down_proj,   // [e][768 k][2048 n] fp32
    const int* __restrict__ offsets,
    const int* __restrict__ tiles,
    const int* __restrict__ tilecount,
    uint16_t* __restrict__ dd)             // [32768+pad][2048] bf16, sorted-pair rows
{
  const int nt = tilecount[0];
  const int na = nt * 8;
  if (blockIdx.x >= na) return;
  const int L  = xcd_unswizzle(blockIdx.x, na);
  const int ti = L % nt, nc = L / nt;
  const int te = tiles[ti];
  const int e = te >> 16, row0 = (te & 0xffff) * 256;
  const int start = offsets[e];
  const int count = offsets[e + 1] - start;
  const int nvalid = min(256, count - row0);

  __shared__ __align__(16) uint16_t aT[2 * 256 * 64];
  __shared__ __align__(16) uint16_t bT[2 * 256 * 64];

  const int t = threadIdx.x, l = t & 63, w = t >> 6;

  const int sub = l >> 3;
  const int xk  = ((l & 7) ^ sub) << 3;

  const uint16_t* srcA[2]; char* dstA[2];
  #pragma unroll
  for (int q = 0; q < 2; ++q) {
    int rl = (w * 2 + q) * 8 + sub;
    srcA[q] = act + (size_t)(start + row0 + rl) * ITER + xk;
    dstA[q] = (char*)aT + (w * 2 + q) * 1024;
  }

  const int brow = t & 255;
  const int kk0  = (t >> 8) * 16;
  const float* wsrc = down_proj + (size_t)e * ITER * HID + nc * 256 + brow; // ldw=HID
  uint16_t* bwr[2];
  #pragma unroll
  for (int s = 0; s < 2; ++s) {
    int kb = (kk0 * 2 + 16 * s) ^ ((brow & 7) << 4);
    bwr[s] = (uint16_t*)((char*)bT + brow * 128 + kb);
  }

  const int wr = w >> 2, wc = w & 3, lr = l & 15, hi = l >> 4;
  const int xorv = (lr & 7) << 4;

  f32x4 acc[4][4];
  #pragma unroll
  for (int mi = 0; mi < 4; ++mi)
    #pragma unroll
    for (int ni = 0; ni < 4; ++ni)
      acc[mi][ni] = (f32x4){0.f, 0.f, 0.f, 0.f};

  float va[16];
  {
    float v0[16];
    const float* wp0 = wsrc + (size_t)kk0 * HID;
    #pragma unroll
    for (int j = 0; j < 16; ++j) v0[j] = wp0[(size_t)j * HID];
    {
      uint4 o0, o1;
      o0.x = cvtpk(v0[0],  v0[1]);  o0.y = cvtpk(v0[2],  v0[3]);
      o0.z = cvtpk(v0[4],  v0[5]);  o0.w = cvtpk(v0[6],  v0[7]);
      o1.x = cvtpk(v0[8],  v0[9]);  o1.y = cvtpk(v0[10], v0[11]);
      o1.z = cvtpk(v0[12], v0[13]); o1.w = cvtpk(v0[14], v0[15]);
      *(uint4*)bwr[0] = o0;
      *(uint4*)bwr[1] = o1;
    }
    #pragma unroll
    for (int q = 0; q < 2; ++q) gl2lds16(srcA[q], dstA[q]);
    const float* wp1 = wsrc + (size_t)(64 + kk0) * HID;
    #pragma unroll
    for (int j = 0; j < 16; ++j) va[j] = wp1[(size_t)j * HID];
  }
  __builtin_amdgcn_sched_barrier(0);
  asm volatile("s_waitcnt vmcnt(16) lgkmcnt(0)");
  __builtin_amdgcn_s_barrier();

  for (int kc = 0; kc < 12; ++kc) {
    const int cur = kc & 1, nxt = cur ^ 1;
    const int k1 = min(kc + 1, 11), k2 = min(kc + 2, 11);
    {
      uint4 o0, o1;
      o0.x = cvtpk(va[0],  va[1]);  o0.y = cvtpk(va[2],  va[3]);
      o0.z = cvtpk(va[4],  va[5]);  o0.w = cvtpk(va[6],  va[7]);
      o1.x = cvtpk(va[8],  va[9]);  o1.y = cvtpk(va[10], va[11]);
      o1.z = cvtpk(va[12], va[13]); o1.w = cvtpk(va[14], va[15]);
      *(uint4*)(bwr[0] + nxt * 16384) = o0;
      *(uint4*)(bwr[1] + nxt * 16384) = o1;
    }
    #pragma unroll
    for (int q = 0; q < 2; ++q)
      gl2lds16(srcA[q] + k1 * 64, dstA[q] + nxt * 32768);
    {
      const float* wp = wsrc + (size_t)(k2 * 64 + kk0) * HID;
      #pragma unroll
      for (int j = 0; j < 16; ++j) va[j] = wp[(size_t)j * HID];
    }
    __builtin_amdgcn_sched_barrier(0);
    __builtin_amdgcn_s_setprio(1);
    const char* aBuf = (const char*)aT + cur * 32768;
    const char* bBuf = (const char*)bT + cur * 32768;
    #pragma unroll
    for (int ks = 0; ks < 2; ++ks) {
      sh8 af[4], bf[4];
      #pragma unroll
      for (int mi = 0; mi < 4; ++mi)
        af[mi] = *(const sh8*)(aBuf +
                   (wr * 64 + mi * 16 + lr) * 128 + ((ks * 64 + hi * 16) ^ xorv));
      #pragma unroll
      for (int ni = 0; ni < 4; ++ni)
        bf[ni] = *(const sh8*)(bBuf +
                   (wc * 64 + ni * 16 + lr) * 128 + ((ks * 64 + hi * 16) ^ xorv));
      #pragma unroll
      for (int mi = 0; mi < 4; ++mi)
        #pragma unroll
        for (int ni = 0; ni < 4; ++ni)
          acc[mi][ni] = MFMA16(af[mi], bf[ni], acc[mi][ni], 0, 0, 0);
    }
    __builtin_amdgcn_s_setprio(0);
    __builtin_amdgcn_sched_barrier(0);
    asm volatile("s_waitcnt vmcnt(16) lgkmcnt(0)");
    __builtin_amdgcn_s_barrier();
  }

  #pragma unroll
  for (int mi = 0; mi < 4; ++mi)
    #pragma unroll
    for (int ni = 0; ni < 4; ++ni)
      #pragma unroll
      for (int j = 0; j < 4; ++j) {
        int row = wr * 64 + mi * 16 + hi * 4 + j;
        if (row < nvalid) {
          int col = nc * 256 + wc * 64 + ni * 16 + lr;
          dd[(size_t)(start + row0 + row) * HID + col] = f2b(acc[mi][ni][j]);
        }
      }
}

// ================= per-token weighted reduction of 8 expert rows =================
__global__ __launch_bounds__(256) void reduce_kernel(
    const uint16_t* __restrict__ dd, const float* __restrict__ topk_w,
    const int* __restrict__ inv, float* __restrict__ out)
{
  const int tok = blockIdx.x;
  const int c   = threadIdx.x * 8;
  float acc[8] = {0.f, 0.f, 0.f, 0.f, 0.f, 0.f, 0.f, 0.f};
  #pragma unroll
  for (int k = 0; k < TOPK; ++k) {
    const int   pos = inv[tok * TOPK + k];
    const float wk  = topk_w[tok * TOPK + k];
    uint4 v = *(const uint4*)&dd[(size_t)pos * HID + c];
    acc[0] += wk * b2f_lo(v.x);  acc[1] += wk * b2f_hi(v.x);
    acc[2] += wk * b2f_lo(v.y);  acc[3] += wk * b2f_hi(v.y);
    acc[4] += wk * b2f_lo(v.z);  acc[5] += wk * b2f_hi(v.z);
    acc[6] += wk * b2f_lo(v.w);  acc[7] += wk * b2f_hi(v.w);
  }
  float4 o0 = {acc[0], acc[1], acc[2], acc[3]};
  float4 o1 = {acc[4], acc[5], acc[6], acc[7]};
  float* op = out + (size_t)tok * HID + c;
  *(float4*)op       = o0;
  *(float4*)(op + 4) = o1;
}

extern "C" void kernel_launch(void* const* d_in, const int* in_sizes, int n_in,
                              void* d_out, int out_size, void* d_ws, size_t ws_size,
                              hipStream_t stream) {
  const float* x         = (const float*)d_in[0];
  const float* gate_w    = (const float*)d_in[1];
  const float* gate_proj = (const float*)d_in[2];
  const float* up_proj   = (const float*)d_in[3];
  const float* down_proj = (const float*)d_in[4];

  float* out    = (float*)d_out;                     // [4096, 2048]
  float* logits = out + (size_t)NTOK * HID;          // [4096, 64]

  // workspace layout (~205 MB total)
  char* ws = (char*)d_ws;
  size_t off = 0;
  uint16_t* xb      = (uint16_t*)(ws + off); off += (size_t)NTOK * HID * 2;                  // 16.8 MB
  uint16_t* act     = (uint16_t*)(ws + off); off += (size_t)(NTOK * TOPK + 256) * ITER * 2;  // 50.6 MB
  uint16_t* dd      = (uint16_t*)(ws + off); off += (size_t)(NTOK * TOPK + 256) * HID * 2;   // 134.9 MB
  int*      topk_id = (int*)  (ws + off); off += (size_t)NTOK * TOPK * 4;
  float*    topk_w  = (float*)(ws + off); off += (size_t)NTOK * TOPK * 4;
  int*      counts  = (int*)  (ws + off); off += 256;
  int*      cursor  = (int*)  (ws + off); off += 256;
  int*      offsets = (int*)  (ws + off); off += 512;
  int*      tiles   = (int*)  (ws + off); off += MAXT * 4;
  int*      tilecount=(int*)  (ws + off); off += 256;
  int*      pair_tok= (int*)  (ws + off); off += (size_t)NTOK * TOPK * 4;
  int*      inv     = (int*)  (ws + off); off += (size_t)NTOK * TOPK * 4;

  zero_kernel   <<<1,    128, 0, stream>>>(counts);
  xcast_kernel  <<<4096, 256, 0, stream>>>(x, xb);
  router_kernel <<<1024, 256, 0, stream>>>(x, gate_w, logits, topk_id, topk_w, counts);
  offsets_kernel<<<1,    64,  0, stream>>>(counts, offsets, tiles, tilecount);
  scatter_kernel<<<128,  256, 0, stream>>>(topk_id, offsets, cursor, pair_tok, inv);

  gateup_kernel<<<MAXT * 6, 1024, 0, stream>>>(xb, gate_proj, up_proj, pair_tok, offsets,
                                               tiles, tilecount, act);
  down_kernel  <<<MAXT * 8, 1024, 0, stream>>>(act, down_proj, offsets,
                                               tiles, tilecount, dd);
  reduce_kernel<<<NTOK, 256, 0, stream>>>(dd, topk_w, inv, out);
}

// Round 16
// 802.381 us; speedup vs baseline: 1.0876x; 1.0876x over previous
//
#include <hip/hip_runtime.h>
#include <hip/hip_bf16.h>
#include <cstdint>

#define NTOK 4096
#define HID  2048
#define ITER 768
#define NEXP 64
#define TOPK 8
#define MAXT 320   // max 256-row tiles: 32768/256 + 63 padding tiles

typedef __attribute__((ext_vector_type(8))) short sh8;
typedef __attribute__((ext_vector_type(4))) float f32x4;

#define MFMA16 __builtin_amdgcn_mfma_f32_16x16x32_bf16

__device__ __forceinline__ uint16_t f2b(float f) {
  union { float f; uint32_t u; } v; v.f = f;
  uint32_t u = v.u;
  u += 0x7FFFu + ((u >> 16) & 1u);   // RNE
  return (uint16_t)(u >> 16);
}

__device__ __forceinline__ float b2f_lo(uint32_t w) {   // bf16 in bits[15:0]
  union { uint32_t u; float f; } v; v.u = w << 16; return v.f;
}
__device__ __forceinline__ float b2f_hi(uint32_t w) {   // bf16 in bits[31:16]
  union { uint32_t u; float f; } v; v.u = w & 0xffff0000u; return v.f;
}

__device__ __forceinline__ uint32_t cvtpk(float lo, float hi) {
  float2 f2; f2.x = lo; f2.y = hi;
  __hip_bfloat162 h = __float22bfloat162_rn(f2);
  union { __hip_bfloat162 h; uint32_t u; } v; v.h = h;
  return v.u;
}

__device__ __forceinline__ void gl2lds16(const void* g, void* l) {
  __builtin_amdgcn_global_load_lds(
      (const __attribute__((address_space(1))) uint32_t*)g,
      (__attribute__((address_space(3))) uint32_t*)l, 16, 0, 0);
}

// m204 bijective XCD-chunked swizzle: hw slot s -> logical L (contiguous L per XCD)
__device__ __forceinline__ int xcd_unswizzle(int s, int na) {
  int q = na >> 3, r = na & 7, x = s & 7, i = s >> 3;
  return (x < r ? x * (q + 1) : r * (q + 1) + (x - r) * q) + i;
}

// ---------------- zero histogram state ----------------
__global__ void zero_kernel(int* __restrict__ cc) {
  cc[threadIdx.x] = 0;   // counts[64] + cursor[64]
}

// ---------------- router: logits + top8 + softmax + histogram + x->bf16 ----------------
// Fused xcast: each lane re-reads its 32-float slice (L1-hot) and writes bf16 coalesced.
__global__ __launch_bounds__(256) void router_kernel(
    const float* __restrict__ x, const float* __restrict__ gate_w,
    float* __restrict__ logits, int* __restrict__ topk_id,
    float* __restrict__ topk_w, int* __restrict__ counts,
    uint16_t* __restrict__ xb)
{
  int lane = threadIdx.x & 63;
  int wv   = threadIdx.x >> 6;
  int t    = blockIdx.x * 4 + wv;
  const float* xr = x + (size_t)t * HID;
  float acc = 0.f;
  #pragma unroll 4
  for (int h = 0; h < HID; h += 4) {
    float4 xv = *(const float4*)(xr + h);
    acc += xv.x * gate_w[(h + 0) * NEXP + lane];
    acc += xv.y * gate_w[(h + 1) * NEXP + lane];
    acc += xv.z * gate_w[(h + 2) * NEXP + lane];
    acc += xv.w * gate_w[(h + 3) * NEXP + lane];
  }
  logits[(size_t)t * NEXP + lane] = acc;

  // bf16 cast of this token's row: lane l owns elements [l*32, l*32+32)
  {
    const float* sp = xr + lane * 32;
    uint16_t* dp = xb + (size_t)t * HID + lane * 32;
    #pragma unroll
    for (int j = 0; j < 4; ++j) {
      float4 a = *(const float4*)(sp + j * 8);
      float4 b = *(const float4*)(sp + j * 8 + 4);
      uint4 o;
      o.x = cvtpk(a.x, a.y);  o.y = cvtpk(a.z, a.w);
      o.z = cvtpk(b.x, b.y);  o.w = cvtpk(b.z, b.w);
      *(uint4*)(dp + j * 8) = o;
    }
  }

  float v = acc;
  float topv[TOPK]; int topi[TOPK];
  #pragma unroll
  for (int k = 0; k < TOPK; ++k) {
    float bv = v; int bi = lane;
    #pragma unroll
    for (int off = 32; off > 0; off >>= 1) {
      float ov = __shfl_xor(bv, off);
      int   oi = __shfl_xor(bi, off);
      if (ov > bv || (ov == bv && oi < bi)) { bv = ov; bi = oi; }
    }
    topv[k] = bv; topi[k] = bi;
    if (lane == bi) v = -3.0e38f;
  }
  float m = topv[0], s = 0.f, w[TOPK];
  #pragma unroll
  for (int k = 0; k < TOPK; ++k) { w[k] = __expf(topv[k] - m); s += w[k]; }
  float inv = 1.f / s;
  if (lane < TOPK) {
    topk_id[t * TOPK + lane] = topi[lane];
    topk_w[t * TOPK + lane]  = w[lane] * inv;
    atomicAdd(&counts[topi[lane]], 1);
  }
}

// ---------------- offsets + dense tile list (256-row granularity) ----------------
__global__ void offsets_kernel(const int* __restrict__ counts, int* __restrict__ offsets,
                               int* __restrict__ tiles, int* __restrict__ tilecount) {
  if (threadIdx.x == 0) {
    int s = 0, nt = 0;
    for (int e = 0; e < NEXP; ++e) {
      offsets[e] = s;
      int c = counts[e];
      for (int rb = 0; rb * 256 < c; ++rb) tiles[nt++] = (e << 16) | rb;
      s += c;
    }
    offsets[NEXP] = s;
    tilecount[0] = nt;
  }
}

// ---------------- scatter pairs grouped by expert (+ inverse map) ----------------
__global__ __launch_bounds__(256) void scatter_kernel(
    const int* __restrict__ topk_id,
    const int* __restrict__ offsets, int* __restrict__ cursor,
    int* __restrict__ pair_tok, int* __restrict__ inv)
{
  int p = blockIdx.x * 256 + threadIdx.x;   // pair index = t*8+k
  int e = topk_id[p];
  int pos = offsets[e] + atomicAdd(&cursor[e], 1);
  pair_tok[pos] = p;
  inv[p] = pos;
}

// ================= gate+up grouped GEMM, BM256 x BN256, fused fp32->bf16 B =================
// 1024 threads (16 waves, 4M x 4N), 1 block/CU. R14-proven 2-barrier loop with
// B reg-prefetch one step deep.
__global__ __launch_bounds__(1024, 4) void gateup_kernel(
    const uint16_t* __restrict__ xb,
    const float* __restrict__ gate_proj,
    const float* __restrict__ up_proj,
    const int* __restrict__ pair_tok,
    const int* __restrict__ offsets,
    const int* __restrict__ tiles,
    const int* __restrict__ tilecount,
    uint16_t* __restrict__ act)
{
  const int nt = tilecount[0];
  const int na = nt * 6;
  if (blockIdx.x >= na) return;
  const int L  = xcd_unswizzle(blockIdx.x, na);
  const int ti = L % nt, nc = L / nt;
  const int te = tiles[ti];
  const int e = te >> 16, row0 = (te & 0xffff) * 256;
  const int start = offsets[e];
  const int count = offsets[e + 1] - start;
  const int nvalid = min(256, count - row0);

  __shared__ __align__(16) uint16_t aT[256 * 64];   // 32 KB
  __shared__ __align__(16) uint16_t bT[256 * 64];   // 32 KB
  __shared__ int s_tok[256];

  const int t = threadIdx.x, l = t & 63, w = t >> 6;
  if (t < 256)
    s_tok[t] = (t < nvalid) ? (pair_tok[start + row0 + t] >> 3) : 0;
  __syncthreads();

  // A staging (gl2lds; pre-swizzled per-lane source). 16 waves x 2 q = 32 row-groups of 8.
  const int sub = l >> 3;
  const int xk  = ((l & 7) ^ sub) << 3;
  const uint16_t* srcA[2]; char* dstA[2];
  #pragma unroll
  for (int q = 0; q < 2; ++q) {
    int rl = (w * 2 + q) * 8 + sub;
    srcA[q] = xb + (size_t)s_tok[rl] * HID + xk;
    dstA[q] = (char*)aT + (w * 2 + q) * 1024;
  }

  // B reg-staging: 1024 threads cover 256 rows x 4 k-quarters (16 k each)
  const int brow = t & 255;
  const int kk0  = (t >> 8) * 16;
  const int rcomb  = nc * 256 + brow;                    // combined interleaved col
  const int n_orig = ((rcomb >> 5) << 4) + (rcomb & 15); // orig col in [0,768)
  const int is_up  = (rcomb >> 4) & 1;
  const float* wsrc = (is_up ? up_proj : gate_proj)
                    + (size_t)e * HID * ITER + n_orig;   // [k][n] fp32, ldw=ITER
  uint16_t* bwr[2];
  #pragma unroll
  for (int s = 0; s < 2; ++s) {
    int kb = (kk0 * 2 + 16 * s) ^ ((brow & 7) << 4);
    bwr[s] = (uint16_t*)((char*)bT + brow * 128 + kb);
  }

  const int wr = w >> 2, wc = w & 3, lr = l & 15, hi = l >> 4;
  const int xorv = (lr & 7) << 4;

  f32x4 acc[4][4];
  #pragma unroll
  for (int mi = 0; mi < 4; ++mi)
    #pragma unroll
    for (int ni = 0; ni < 4; ++ni)
      acc[mi][ni] = (f32x4){0.f, 0.f, 0.f, 0.f};

  // prologue: prefetch kc=0 B
  float va[16];
  {
    const float* wp = wsrc + (size_t)kk0 * ITER;
    #pragma unroll
    for (int j = 0; j < 16; ++j) va[j] = wp[(size_t)j * ITER];
  }

  for (int kc = 0; kc < 32; ++kc) {
    __syncthreads();
    // consume prefetched va: cvt + swizzled ds_write
    {
      uint4 o0, o1;
      o0.x = cvtpk(va[0],  va[1]);  o0.y = cvtpk(va[2],  va[3]);
      o0.z = cvtpk(va[4],  va[5]);  o0.w = cvtpk(va[6],  va[7]);
      o1.x = cvtpk(va[8],  va[9]);  o1.y = cvtpk(va[10], va[11]);
      o1.z = cvtpk(va[12], va[13]); o1.w = cvtpk(va[14], va[15]);
      *(uint4*)bwr[0] = o0;
      *(uint4*)bwr[1] = o1;
    }
    #pragma unroll
    for (int q = 0; q < 2; ++q)
      gl2lds16(srcA[q] + kc * 64, dstA[q]);
    __syncthreads();
    // issue next K-step's B loads: in flight under the MFMA cluster below
    if (kc + 1 < 32) {
      const float* wp = wsrc + (size_t)((kc + 1) * 64 + kk0) * ITER;
      #pragma unroll
      for (int j = 0; j < 16; ++j) va[j] = wp[(size_t)j * ITER];
    }
    __builtin_amdgcn_sched_barrier(0);   // keep load issue above the MFMAs
    #pragma unroll
    for (int ks = 0; ks < 2; ++ks) {
      sh8 af[4], bf[4];
      #pragma unroll
      for (int mi = 0; mi < 4; ++mi)
        af[mi] = *(const sh8*)((const char*)aT +
                   (wr * 64 + mi * 16 + lr) * 128 + ((ks * 64 + hi * 16) ^ xorv));
      #pragma unroll
      for (int ni = 0; ni < 4; ++ni)
        bf[ni] = *(const sh8*)((const char*)bT +
                   (wc * 64 + ni * 16 + lr) * 128 + ((ks * 64 + hi * 16) ^ xorv));
      #pragma unroll
      for (int mi = 0; mi < 4; ++mi)
        #pragma unroll
        for (int ni = 0; ni < 4; ++ni)
          acc[mi][ni] = MFMA16(af[mi], bf[ni], acc[mi][ni], 0, 0, 0);
    }
  }

  // epilogue: combined col blocks pair (even=gate, odd=up)
  #pragma unroll
  for (int mi = 0; mi < 4; ++mi)
    #pragma unroll
    for (int p = 0; p < 2; ++p)
      #pragma unroll
      for (int j = 0; j < 4; ++j) {
        int row = wr * 64 + mi * 16 + hi * 4 + j;
        if (row < nvalid) {
          float g = acc[mi][2 * p][j], u = acc[mi][2 * p + 1][j];
          float a = (g / (1.f + __expf(-g))) * u;
          int col = nc * 128 + (wc * 2 + p) * 16 + lr;
          act[(size_t)(start + row0 + row) * ITER + col] = f2b(a);
        }
      }
}

// ================= down grouped GEMM, BM256 x BN256, fused fp32->bf16 B =================
// 1024 threads; dense bf16 rows out (no atomics)
__global__ __launch_bounds__(1024, 4) void down_kernel(
    const uint16_t* __restrict__ act,
    const float* __restrict__ down_proj,   // [e][768 k][2048 n] fp32
    const int* __restrict__ offsets,
    const int* __restrict__ tiles,
    const int* __restrict__ tilecount,
    uint16_t* __restrict__ dd)             // [32768+pad][2048] bf16, sorted-pair rows
{
  const int nt = tilecount[0];
  const int na = nt * 8;
  if (blockIdx.x >= na) return;
  const int L  = xcd_unswizzle(blockIdx.x, na);
  const int ti = L % nt, nc = L / nt;
  const int te = tiles[ti];
  const int e = te >> 16, row0 = (te & 0xffff) * 256;
  const int start = offsets[e];
  const int count = offsets[e + 1] - start;
  const int nvalid = min(256, count - row0);

  __shared__ __align__(16) uint16_t aT[256 * 64];
  __shared__ __align__(16) uint16_t bT[256 * 64];

  const int t = threadIdx.x, l = t & 63, w = t >> 6;

  const int sub = l >> 3;
  const int xk  = ((l & 7) ^ sub) << 3;

  const uint16_t* srcA[2]; char* dstA[2];
  #pragma unroll
  for (int q = 0; q < 2; ++q) {
    int rl = (w * 2 + q) * 8 + sub;
    srcA[q] = act + (size_t)(start + row0 + rl) * ITER + xk;
    dstA[q] = (char*)aT + (w * 2 + q) * 1024;
  }

  const int brow = t & 255;
  const int kk0  = (t >> 8) * 16;
  const float* wsrc = down_proj + (size_t)e * ITER * HID + nc * 256 + brow; // ldw=HID
  uint16_t* bwr[2];
  #pragma unroll
  for (int s = 0; s < 2; ++s) {
    int kb = (kk0 * 2 + 16 * s) ^ ((brow & 7) << 4);
    bwr[s] = (uint16_t*)((char*)bT + brow * 128 + kb);
  }

  const int wr = w >> 2, wc = w & 3, lr = l & 15, hi = l >> 4;
  const int xorv = (lr & 7) << 4;

  f32x4 acc[4][4];
  #pragma unroll
  for (int mi = 0; mi < 4; ++mi)
    #pragma unroll
    for (int ni = 0; ni < 4; ++ni)
      acc[mi][ni] = (f32x4){0.f, 0.f, 0.f, 0.f};

  float va[16];
  {
    const float* wp = wsrc + (size_t)kk0 * HID;
    #pragma unroll
    for (int j = 0; j < 16; ++j) va[j] = wp[(size_t)j * HID];
  }

  for (int kc = 0; kc < 12; ++kc) {
    __syncthreads();
    {
      uint4 o0, o1;
      o0.x = cvtpk(va[0],  va[1]);  o0.y = cvtpk(va[2],  va[3]);
      o0.z = cvtpk(va[4],  va[5]);  o0.w = cvtpk(va[6],  va[7]);
      o1.x = cvtpk(va[8],  va[9]);  o1.y = cvtpk(va[10], va[11]);
      o1.z = cvtpk(va[12], va[13]); o1.w = cvtpk(va[14], va[15]);
      *(uint4*)bwr[0] = o0;
      *(uint4*)bwr[1] = o1;
    }
    #pragma unroll
    for (int q = 0; q < 2; ++q)
      gl2lds16(srcA[q] + kc * 64, dstA[q]);
    __syncthreads();
    if (kc + 1 < 12) {
      const float* wp = wsrc + (size_t)((kc + 1) * 64 + kk0) * HID;
      #pragma unroll
      for (int j = 0; j < 16; ++j) va[j] = wp[(size_t)j * HID];
    }
    __builtin_amdgcn_sched_barrier(0);
    #pragma unroll
    for (int ks = 0; ks < 2; ++ks) {
      sh8 af[4], bf[4];
      #pragma unroll
      for (int mi = 0; mi < 4; ++mi)
        af[mi] = *(const sh8*)((const char*)aT +
                   (wr * 64 + mi * 16 + lr) * 128 + ((ks * 64 + hi * 16) ^ xorv));
      #pragma unroll
      for (int ni = 0; ni < 4; ++ni)
        bf[ni] = *(const sh8*)((const char*)bT +
                   (wc * 64 + ni * 16 + lr) * 128 + ((ks * 64 + hi * 16) ^ xorv));
      #pragma unroll
      for (int mi = 0; mi < 4; ++mi)
        #pragma unroll
        for (int ni = 0; ni < 4; ++ni)
          acc[mi][ni] = MFMA16(af[mi], bf[ni], acc[mi][ni], 0, 0, 0);
    }
  }

  #pragma unroll
  for (int mi = 0; mi < 4; ++mi)
    #pragma unroll
    for (int ni = 0; ni < 4; ++ni)
      #pragma unroll
      for (int j = 0; j < 4; ++j) {
        int row = wr * 64 + mi * 16 + hi * 4 + j;
        if (row < nvalid) {
          int col = nc * 256 + wc * 64 + ni * 16 + lr;
          dd[(size_t)(start + row0 + row) * HID + col] = f2b(acc[mi][ni][j]);
        }
      }
}

// ================= per-token weighted reduction of 8 expert rows =================
__global__ __launch_bounds__(256) void reduce_kernel(
    const uint16_t* __restrict__ dd, const float* __restrict__ topk_w,
    const int* __restrict__ inv, float* __restrict__ out)
{
  const int tok = blockIdx.x;
  const int c   = threadIdx.x * 8;
  float acc[8] = {0.f, 0.f, 0.f, 0.f, 0.f, 0.f, 0.f, 0.f};
  #pragma unroll
  for (int k = 0; k < TOPK; ++k) {
    const int   pos = inv[tok * TOPK + k];
    const float wk  = topk_w[tok * TOPK + k];
    uint4 v = *(const uint4*)&dd[(size_t)pos * HID + c];
    acc[0] += wk * b2f_lo(v.x);  acc[1] += wk * b2f_hi(v.x);
    acc[2] += wk * b2f_lo(v.y);  acc[3] += wk * b2f_hi(v.y);
    acc[4] += wk * b2f_lo(v.z);  acc[5] += wk * b2f_hi(v.z);
    acc[6] += wk * b2f_lo(v.w);  acc[7] += wk * b2f_hi(v.w);
  }
  float4 o0 = {acc[0], acc[1], acc[2], acc[3]};
  float4 o1 = {acc[4], acc[5], acc[6], acc[7]};
  float* op = out + (size_t)tok * HID + c;
  *(float4*)op       = o0;
  *(float4*)(op + 4) = o1;
}

extern "C" void kernel_launch(void* const* d_in, const int* in_sizes, int n_in,
                              void* d_out, int out_size, void* d_ws, size_t ws_size,
                              hipStream_t stream) {
  const float* x         = (const float*)d_in[0];
  const float* gate_w    = (const float*)d_in[1];
  const float* gate_proj = (const float*)d_in[2];
  const float* up_proj   = (const float*)d_in[3];
  const float* down_proj = (const float*)d_in[4];

  float* out    = (float*)d_out;                     // [4096, 2048]
  float* logits = out + (size_t)NTOK * HID;          // [4096, 64]

  // workspace layout (~205 MB total)
  char* ws = (char*)d_ws;
  size_t off = 0;
  uint16_t* xb      = (uint16_t*)(ws + off); off += (size_t)NTOK * HID * 2;                  // 16.8 MB
  uint16_t* act     = (uint16_t*)(ws + off); off += (size_t)(NTOK * TOPK + 256) * ITER * 2;  // 50.6 MB
  uint16_t* dd      = (uint16_t*)(ws + off); off += (size_t)(NTOK * TOPK + 256) * HID * 2;   // 134.9 MB
  int*      topk_id = (int*)  (ws + off); off += (size_t)NTOK * TOPK * 4;
  float*    topk_w  = (float*)(ws + off); off += (size_t)NTOK * TOPK * 4;
  int*      counts  = (int*)  (ws + off); off += 256;
  int*      cursor  = (int*)  (ws + off); off += 256;
  int*      offsets = (int*)  (ws + off); off += 512;
  int*      tiles   = (int*)  (ws + off); off += MAXT * 4;
  int*      tilecount=(int*)  (ws + off); off += 256;
  int*      pair_tok= (int*)  (ws + off); off += (size_t)NTOK * TOPK * 4;
  int*      inv     = (int*)  (ws + off); off += (size_t)NTOK * TOPK * 4;

  zero_kernel   <<<1,    128, 0, stream>>>(counts);
  router_kernel <<<1024, 256, 0, stream>>>(x, gate_w, logits, topk_id, topk_w, counts, xb);
  offsets_kernel<<<1,    64,  0, stream>>>(counts, offsets, tiles, tilecount);
  scatter_kernel<<<128,  256, 0, stream>>>(topk_id, offsets, cursor, pair_tok, inv);

  gateup_kernel<<<MAXT * 6, 1024, 0, stream>>>(xb, gate_proj, up_proj, pair_tok, offsets,
                                               tiles, tilecount, act);
  down_kernel  <<<MAXT * 8, 1024, 0, stream>>>(act, down_proj, offsets,
                                               tiles, tilecount, dd);
  reduce_kernel<<<NTOK, 256, 0, stream>>>(dd, topk_w, inv, out);
}